// Round 7
// baseline (139.203 us; speedup 1.0000x reference)
//
#include <hip/hip_runtime.h>
#include <stdint.h>

#define N_BATCH 4096
#define NCELL (4096 * 14 * 14)   // 802816
#define CPB 256
#define NBLOCKS (NCELL / CPB)    // 3136

// 1/14; reference does x/14.0f. Verified absmax 0.0 with reciprocal-mul.
#define INV_S 0.07142857142857142f

// ws layout: [0, NBLOCKS) float partials x4 interleaved (float4 per block),
// then flag (int), then done-counter (uint).
#define WS_FLAG_OFF (NBLOCKS * 4)          // in floats
#define WS_CTR_OFF  (NBLOCKS * 4 + 1)

// ---------------------------------------------------------------------------
// Kernel 1: detect mask storage layout + zero the done-counter.
// flag: 0 = int32 (0/1), 1 = float32 (0.0/1.0), 2 = uint8 (numpy bool)
// ---------------------------------------------------------------------------
__global__ void detect_and_init(const unsigned int* __restrict__ mask_words,
                                int* __restrict__ flag,
                                unsigned int* __restrict__ ctr) {
    __shared__ int s_notInt, s_notFloat;
    const int tid = threadIdx.x;
    if (tid == 0) { s_notInt = 0; s_notFloat = 0; *ctr = 0u; }
    __syncthreads();
    int notInt = 0, notFloat = 0;
    for (int i = tid; i < 1024; i += 256) {
        const unsigned int u = mask_words[i];
        if (u > 1u) notInt = 1;
        if (u != 0u && u != 0x3F800000u) notFloat = 1;
    }
    if (notInt)   atomicOr(&s_notInt, 1);
    if (notFloat) atomicOr(&s_notFloat, 1);
    __syncthreads();
    if (tid == 0) *flag = (!s_notInt) ? 0 : ((!s_notFloat) ? 1 : 2);
}

// ---------------------------------------------------------------------------
// async global->LDS 16B stage: l_wavebase must be wave-uniform; HW adds lane*16.
// ---------------------------------------------------------------------------
__device__ __forceinline__ void stage16(const float4* g_lane, float4* l_wavebase, int lane) {
#if __has_builtin(__builtin_amdgcn_global_load_lds)
    __builtin_amdgcn_global_load_lds((const __attribute__((address_space(1))) void*)g_lane,
                                     (__attribute__((address_space(3))) void*)l_wavebase,
                                     16, 0, 0);
#else
    l_wavebase[lane] = *g_lane;
#endif
}

__device__ __forceinline__ float iou_xyxy(const float a0, const float a1,
                                          const float a2, const float a3,
                                          const float b0, const float b1,
                                          const float b2, const float b3) {
    const float ltx = fmaxf(a0, b0), lty = fmaxf(a1, b1);
    const float rbx = fminf(a2, b2), rby = fminf(a3, b3);
    const float wx = fmaxf(rbx - ltx, 0.0f), wy = fmaxf(rby - lty, 0.0f);
    const float inter = wx * wy;
    const float area_a = (a2 - a0) * (a3 - a1);
    const float area_b = (b2 - b0) * (b3 - b1);
    return inter / (area_a + area_b - inter);
}

// ---------------------------------------------------------------------------
// Kernel 2: main loss + last-block finalize.
// ---------------------------------------------------------------------------
__global__ __launch_bounds__(256) void yolo_loss_main(
    const float* __restrict__ pred,
    const float* __restrict__ tbox,
    const float* __restrict__ tcls,
    const void* __restrict__ maskp,
    const int* __restrict__ flagp,
    float* __restrict__ pf,              // partials: 4 floats per block
    unsigned int* __restrict__ ctr,
    float* __restrict__ out) {

    __shared__ __align__(16) float s_pred[CPB * 30];  // 30 KB
    __shared__ float s_mf[CPB];
    __shared__ float s_red[4][4];
    __shared__ int s_last;

    const int t = threadIdx.x;
    const int lane = t & 63;
    const int cell0 = blockIdx.x * CPB;
    const int idx = cell0 + t;
    const int flag = *flagp;

    // ---- async stage pred -> LDS (8 x 16B per thread equivalent) ----
    const float4* pg = (const float4*)(pred + (size_t)cell0 * 30);
    float4* sp4 = (float4*)s_pred;
    const int wbase = t & ~63;   // wave-uniform
    #pragma unroll
    for (int k = 0; k < 7; ++k)
        stage16(pg + k * 256 + t, sp4 + k * 256 + wbase, lane);
    if (t < 128)                 // tail half-chunk (1920 = 7.5*256), waves 0-1
        stage16(pg + 1792 + t, sp4 + 1792 + wbase, lane);

    // ---- tcls into registers (coalesced), overlaps with async staging ----
    const float4* cg = (const float4*)(tcls + (size_t)cell0 * 20);
    const float4 c0 = cg[t];
    const float4 c1 = cg[t + 256];
    const float4 c2 = cg[t + 512];
    const float4 c3 = cg[t + 768];
    const float4 c4 = cg[t + 1024];

    const float4 tb = ((const float4*)tbox)[idx];

    bool m;
    if (flag == 0)      m = ((const int*)maskp)[idx] != 0;
    else if (flag == 1) m = ((const float*)maskp)[idx] != 0.0f;
    else                m = ((const unsigned char*)maskp)[idx] != 0;
    const float mf = m ? 1.0f : 0.0f;
    s_mf[t] = mf;

    __syncthreads();   // drains vmcnt (async stages) + lgkmcnt

    // ---- phase 2: cls loss, tcls registers vs LDS pred ----
    float cls = 0.0f;
    {
        #define CLS_STEP(K, CK)                                        \
        {                                                              \
            const int e  = t + (K) * 256;                              \
            const int c  = e / 5;                                      \
            const int j0 = (e - c * 5) * 4;                            \
            const float* sp = &s_pred[c * 30 + 10 + j0];               \
            const float w = s_mf[c];                                   \
            const float d0 = sp[0] - (CK).x;                           \
            const float d1 = sp[1] - (CK).y;                           \
            const float d2 = sp[2] - (CK).z;                           \
            const float d3 = sp[3] - (CK).w;                           \
            cls += w * (d0 * d0 + d1 * d1 + d2 * d2 + d3 * d3);        \
        }
        CLS_STEP(0, c0) CLS_STEP(1, c1) CLS_STEP(2, c2)
        CLS_STEP(3, c3) CLS_STEP(4, c4)
        #undef CLS_STEP
    }

    // ---- phase 3: per-cell box math from LDS ----
    float pr[10];
    #pragma unroll
    for (int i = 0; i < 10; ++i) pr[i] = s_pred[t * 30 + i];

    float noobj = (1.0f - mf) * (pr[4] * pr[4] + pr[9] * pr[9]);

    const float b1x0 = pr[0] * INV_S - 0.5f * pr[2];
    const float b1y0 = pr[1] * INV_S - 0.5f * pr[3];
    const float b1x1 = pr[0] * INV_S + 0.5f * pr[2];
    const float b1y1 = pr[1] * INV_S + 0.5f * pr[3];
    const float b2x0 = pr[5] * INV_S - 0.5f * pr[7];
    const float b2y0 = pr[6] * INV_S - 0.5f * pr[8];
    const float b2x1 = pr[5] * INV_S + 0.5f * pr[7];
    const float b2y1 = pr[6] * INV_S + 0.5f * pr[8];
    const float btx0 = tb.x * INV_S - 0.5f * tb.z;
    const float bty0 = tb.y * INV_S - 0.5f * tb.w;
    const float btx1 = tb.x * INV_S + 0.5f * tb.z;
    const float bty1 = tb.y * INV_S + 0.5f * tb.w;

    const float i1 = iou_xyxy(b1x0, b1y0, b1x1, b1y1, btx0, bty0, btx1, bty1);
    const float i2 = iou_xyxy(b2x0, b2y0, b2x1, b2y1, btx0, bty0, btx1, bty1);

    const bool take1 = i1 > i2;
    const float best_iou = take1 ? i1 : i2;
    const float bx = take1 ? pr[0] : pr[5];
    const float by = take1 ? pr[1] : pr[6];
    const float bw = take1 ? pr[2] : pr[7];
    const float bh = take1 ? pr[3] : pr[8];
    const float bc = take1 ? pr[4] : pr[9];

    const float dx = bx - tb.x;
    const float dy = by - tb.y;
    const float pw = m ? sqrtf(bw) : 1.0f;
    const float ph = m ? sqrtf(bh) : 1.0f;
    const float tw = m ? sqrtf(tb.z) : 1.0f;
    const float th = m ? sqrtf(tb.w) : 1.0f;
    float reg = mf * (dx * dx + dy * dy)
              + mf * ((pw - tw) * (pw - tw) + (ph - th) * (ph - th));

    const float dc = bc - best_iou;
    float conf = mf * dc * dc;

    // ---- wave + block reduction ----
    #pragma unroll
    for (int off = 32; off > 0; off >>= 1) {
        reg   += __shfl_down(reg,   off);
        conf  += __shfl_down(conf,  off);
        noobj += __shfl_down(noobj, off);
        cls   += __shfl_down(cls,   off);
    }
    const int wid = t >> 6;
    if (lane == 0) {
        s_red[0][wid] = reg; s_red[1][wid] = conf;
        s_red[2][wid] = noobj; s_red[3][wid] = cls;
    }
    __syncthreads();

    // ---- publish partial (AGENT-scope coherent stores) + done counter ----
    if (t == 0) {
        float v0 = 0.f, v1 = 0.f, v2 = 0.f, v3 = 0.f;
        #pragma unroll
        for (int w = 0; w < 4; ++w) {
            v0 += s_red[0][w]; v1 += s_red[1][w];
            v2 += s_red[2][w]; v3 += s_red[3][w];
        }
        float* dst = pf + (size_t)blockIdx.x * 4;
        __hip_atomic_store(&dst[0], v0, __ATOMIC_RELAXED, __HIP_MEMORY_SCOPE_AGENT);
        __hip_atomic_store(&dst[1], v1, __ATOMIC_RELAXED, __HIP_MEMORY_SCOPE_AGENT);
        __hip_atomic_store(&dst[2], v2, __ATOMIC_RELAXED, __HIP_MEMORY_SCOPE_AGENT);
        __hip_atomic_store(&dst[3], v3, __ATOMIC_RELAXED, __HIP_MEMORY_SCOPE_AGENT);
        const unsigned prev =
            __hip_atomic_fetch_add(ctr, 1u, __ATOMIC_ACQ_REL, __HIP_MEMORY_SCOPE_AGENT);
        s_last = (prev == (unsigned)(NBLOCKS - 1));
    }
    __syncthreads();

    // ---- last block: reduce all partials and write the 5 outputs ----
    if (s_last) {
        double r = 0.0, cf = 0.0, no = 0.0, cl = 0.0;
        for (int i = t; i < NBLOCKS; i += 256) {
            const float* src = pf + (size_t)i * 4;
            r  += (double)__hip_atomic_load(&src[0], __ATOMIC_RELAXED, __HIP_MEMORY_SCOPE_AGENT);
            cf += (double)__hip_atomic_load(&src[1], __ATOMIC_RELAXED, __HIP_MEMORY_SCOPE_AGENT);
            no += (double)__hip_atomic_load(&src[2], __ATOMIC_RELAXED, __HIP_MEMORY_SCOPE_AGENT);
            cl += (double)__hip_atomic_load(&src[3], __ATOMIC_RELAXED, __HIP_MEMORY_SCOPE_AGENT);
        }
        #pragma unroll
        for (int off = 32; off > 0; off >>= 1) {
            r  += __shfl_down(r,  off);
            cf += __shfl_down(cf, off);
            no += __shfl_down(no, off);
            cl += __shfl_down(cl, off);
        }
        __shared__ double s_d[4][4];
        if (lane == 0) { s_d[0][wid] = r; s_d[1][wid] = cf; s_d[2][wid] = no; s_d[3][wid] = cl; }
        __syncthreads();
        if (t == 0) {
            double R = 0, CF = 0, NO = 0, CL = 0;
            #pragma unroll
            for (int w = 0; w < 4; ++w) { R += s_d[0][w]; CF += s_d[1][w]; NO += s_d[2][w]; CL += s_d[3][w]; }
            const float invN = 1.0f / (float)N_BATCH;
            const float regf   = (float)R  * invN;
            const float conff  = (float)CF * invN;
            const float noobjf = (float)NO * invN;
            const float clsf   = (float)CL * invN;
            out[0] = 5.0f * regf + conff + 0.5f * noobjf + clsf;
            out[1] = regf;
            out[2] = conff;
            out[3] = noobjf;
            out[4] = clsf;
        }
    }
}

extern "C" void kernel_launch(void* const* d_in, const int* in_sizes, int n_in,
                              void* d_out, int out_size, void* d_ws, size_t ws_size,
                              hipStream_t stream) {
    const float* pred = (const float*)d_in[0];
    const float* tbox = (const float*)d_in[1];
    const float* tcls = (const float*)d_in[2];
    const void*  mask = (const void*)d_in[3];
    float* out = (float*)d_out;

    float* pf = (float*)d_ws;
    int* flag = (int*)d_ws + WS_FLAG_OFF;
    unsigned int* ctr = (unsigned int*)d_ws + WS_CTR_OFF;

    detect_and_init<<<1, 256, 0, stream>>>((const unsigned int*)mask, flag, ctr);
    yolo_loss_main<<<NBLOCKS, 256, 0, stream>>>(pred, tbox, tcls, mask, flag, pf, ctr, out);
}

// Round 8
// 41.848 us; speedup vs baseline: 3.3264x; 3.3264x over previous
//
#include <hip/hip_runtime.h>

#define N_BATCH 4096
#define NCELL (4096 * 14 * 14)   // 802816
#define CPB 256
#define NBLOCKS (NCELL / CPB)    // 3136

// 1/14; reference does x/14.0f. Verified absmax 0.0 with reciprocal-mul.
#define INV_S 0.07142857142857142f

// ---------------------------------------------------------------------------
// Kernel 1: detect mask storage layout.
// flag: 0 = int32 (0/1), 1 = float32 (0.0/1.0), 2 = uint8 (numpy bool)
// Scans first 1024 words (4 KB) — in-bounds for every candidate layout.
// ---------------------------------------------------------------------------
__global__ void detect_flag(const unsigned int* __restrict__ mask_words,
                            int* __restrict__ flag) {
    __shared__ int s_notInt, s_notFloat;
    const int tid = threadIdx.x;
    if (tid == 0) { s_notInt = 0; s_notFloat = 0; }
    __syncthreads();
    int notInt = 0, notFloat = 0;
    for (int i = tid; i < 1024; i += 256) {
        const unsigned int u = mask_words[i];
        if (u > 1u) notInt = 1;
        if (u != 0u && u != 0x3F800000u) notFloat = 1;
    }
    if (notInt)   atomicOr(&s_notInt, 1);
    if (notFloat) atomicOr(&s_notFloat, 1);
    __syncthreads();
    if (tid == 0) *flag = (!s_notInt) ? 0 : ((!s_notFloat) ? 1 : 2);
}

// ---------------------------------------------------------------------------
// async global->LDS 16B stage: l_wavebase must be wave-uniform; HW adds lane*16.
// Zero VGPR cost per stage -> all 8 pred stages stay in flight regardless of
// register allocation (the R6 failure mode).
// ---------------------------------------------------------------------------
__device__ __forceinline__ void stage16(const float4* g_lane, float4* l_wavebase, int lane) {
#if __has_builtin(__builtin_amdgcn_global_load_lds)
    __builtin_amdgcn_global_load_lds((const __attribute__((address_space(1))) void*)g_lane,
                                     (__attribute__((address_space(3))) void*)l_wavebase,
                                     16, 0, 0);
#else
    l_wavebase[lane] = *g_lane;
#endif
}

__device__ __forceinline__ float iou_xyxy(const float a0, const float a1,
                                          const float a2, const float a3,
                                          const float b0, const float b1,
                                          const float b2, const float b3) {
    const float ltx = fmaxf(a0, b0), lty = fmaxf(a1, b1);
    const float rbx = fminf(a2, b2), rby = fminf(a3, b3);
    const float wx = fmaxf(rbx - ltx, 0.0f), wy = fmaxf(rby - lty, 0.0f);
    const float inter = wx * wy;
    const float area_a = (a2 - a0) * (a3 - a1);
    const float area_b = (b2 - b0) * (b3 - b1);
    return inter / (area_a + area_b - inter);
}

// ---------------------------------------------------------------------------
// Kernel 2: main loss. Block = 256 cells. pred -> LDS via async
// global_load_lds (8 stages, no VGPRs); tcls/tbox/mask into registers;
// ONE barrier drains everything. No atomics: one float4 partial per block.
// ---------------------------------------------------------------------------
__global__ __launch_bounds__(256) void yolo_loss_main(
    const float* __restrict__ pred,
    const float* __restrict__ tbox,
    const float* __restrict__ tcls,
    const void* __restrict__ maskp,
    const int* __restrict__ flagp,
    float4* __restrict__ partial) {

    __shared__ __align__(16) float s_pred[CPB * 30];  // 30 KB
    __shared__ float s_mf[CPB];
    __shared__ float s_red[4][4];

    const int t = threadIdx.x;
    const int lane = t & 63;
    const int cell0 = blockIdx.x * CPB;
    const int idx = cell0 + t;
    const int flag = *flagp;

    // ---- async stage pred -> LDS (7.5 * 256 float4 per block) ----
    const float4* pg = (const float4*)(pred + (size_t)cell0 * 30);
    float4* sp4 = (float4*)s_pred;
    const int wbase = t & ~63;   // wave-uniform LDS base
    #pragma unroll
    for (int k = 0; k < 7; ++k)
        stage16(pg + k * 256 + t, sp4 + k * 256 + wbase, lane);
    if (t < 128)                 // tail half-chunk, waves 0-1 fully active
        stage16(pg + 1792 + t, sp4 + 1792 + wbase, lane);

    // ---- tcls into registers (coalesced), overlaps the async stages ----
    const float4* cg = (const float4*)(tcls + (size_t)cell0 * 20);
    const float4 c0 = cg[t];
    const float4 c1 = cg[t + 256];
    const float4 c2 = cg[t + 512];
    const float4 c3 = cg[t + 768];
    const float4 c4 = cg[t + 1024];

    const float4 tb = ((const float4*)tbox)[idx];

    bool m;
    if (flag == 0)      m = ((const int*)maskp)[idx] != 0;
    else if (flag == 1) m = ((const float*)maskp)[idx] != 0.0f;
    else                m = ((const unsigned char*)maskp)[idx] != 0;
    const float mf = m ? 1.0f : 0.0f;
    s_mf[t] = mf;

    __syncthreads();   // drains vmcnt (async stages) + lgkmcnt

    // ---- phase 2: cls loss, tcls registers vs LDS pred ----
    float cls = 0.0f;
    {
        #define CLS_STEP(K, CK)                                        \
        {                                                              \
            const int e  = t + (K) * 256;                              \
            const int c  = e / 5;                                      \
            const int j0 = (e - c * 5) * 4;                            \
            const float* sp = &s_pred[c * 30 + 10 + j0];               \
            const float w = s_mf[c];                                   \
            const float d0 = sp[0] - (CK).x;                           \
            const float d1 = sp[1] - (CK).y;                           \
            const float d2 = sp[2] - (CK).z;                           \
            const float d3 = sp[3] - (CK).w;                           \
            cls += w * (d0 * d0 + d1 * d1 + d2 * d2 + d3 * d3);        \
        }
        CLS_STEP(0, c0) CLS_STEP(1, c1) CLS_STEP(2, c2)
        CLS_STEP(3, c3) CLS_STEP(4, c4)
        #undef CLS_STEP
    }

    // ---- phase 3: per-cell box math from LDS ----
    float pr[10];
    #pragma unroll
    for (int i = 0; i < 10; ++i) pr[i] = s_pred[t * 30 + i];

    float noobj = (1.0f - mf) * (pr[4] * pr[4] + pr[9] * pr[9]);

    const float b1x0 = pr[0] * INV_S - 0.5f * pr[2];
    const float b1y0 = pr[1] * INV_S - 0.5f * pr[3];
    const float b1x1 = pr[0] * INV_S + 0.5f * pr[2];
    const float b1y1 = pr[1] * INV_S + 0.5f * pr[3];
    const float b2x0 = pr[5] * INV_S - 0.5f * pr[7];
    const float b2y0 = pr[6] * INV_S - 0.5f * pr[8];
    const float b2x1 = pr[5] * INV_S + 0.5f * pr[7];
    const float b2y1 = pr[6] * INV_S + 0.5f * pr[8];
    const float btx0 = tb.x * INV_S - 0.5f * tb.z;
    const float bty0 = tb.y * INV_S - 0.5f * tb.w;
    const float btx1 = tb.x * INV_S + 0.5f * tb.z;
    const float bty1 = tb.y * INV_S + 0.5f * tb.w;

    const float i1 = iou_xyxy(b1x0, b1y0, b1x1, b1y1, btx0, bty0, btx1, bty1);
    const float i2 = iou_xyxy(b2x0, b2y0, b2x1, b2y1, btx0, bty0, btx1, bty1);

    const bool take1 = i1 > i2;
    const float best_iou = take1 ? i1 : i2;
    const float bx = take1 ? pr[0] : pr[5];
    const float by = take1 ? pr[1] : pr[6];
    const float bw = take1 ? pr[2] : pr[7];
    const float bh = take1 ? pr[3] : pr[8];
    const float bc = take1 ? pr[4] : pr[9];

    const float dx = bx - tb.x;
    const float dy = by - tb.y;
    const float pw = m ? sqrtf(bw) : 1.0f;
    const float ph = m ? sqrtf(bh) : 1.0f;
    const float tw = m ? sqrtf(tb.z) : 1.0f;
    const float th = m ? sqrtf(tb.w) : 1.0f;
    float reg = mf * (dx * dx + dy * dy)
              + mf * ((pw - tw) * (pw - tw) + (ph - th) * (ph - th));

    const float dc = bc - best_iou;
    float conf = mf * dc * dc;

    // ---- wave + block reduction ----
    #pragma unroll
    for (int off = 32; off > 0; off >>= 1) {
        reg   += __shfl_down(reg,   off);
        conf  += __shfl_down(conf,  off);
        noobj += __shfl_down(noobj, off);
        cls   += __shfl_down(cls,   off);
    }
    const int wid = t >> 6;
    if (lane == 0) {
        s_red[0][wid] = reg; s_red[1][wid] = conf;
        s_red[2][wid] = noobj; s_red[3][wid] = cls;
    }
    __syncthreads();
    if (t == 0) {
        float r = 0.0f, cf = 0.0f, no = 0.0f, cl = 0.0f;
        #pragma unroll
        for (int w = 0; w < 4; ++w) {
            r += s_red[0][w]; cf += s_red[1][w];
            no += s_red[2][w]; cl += s_red[3][w];
        }
        partial[blockIdx.x] = make_float4(r, cf, no, cl);
    }
}

// ---------------------------------------------------------------------------
// Kernel 3: finalize — reduce block partials (double accum), normalize.
// ---------------------------------------------------------------------------
__global__ __launch_bounds__(256) void yolo_finalize(
    const float4* __restrict__ partial,
    float* __restrict__ out) {
    const int t = threadIdx.x;
    double r = 0.0, cf = 0.0, no = 0.0, cl = 0.0;
    for (int i = t; i < NBLOCKS; i += 256) {
        const float4 p = partial[i];
        r += (double)p.x; cf += (double)p.y; no += (double)p.z; cl += (double)p.w;
    }
    #pragma unroll
    for (int off = 32; off > 0; off >>= 1) {
        r  += __shfl_down(r,  off);
        cf += __shfl_down(cf, off);
        no += __shfl_down(no, off);
        cl += __shfl_down(cl, off);
    }
    __shared__ double s[4][4];
    const int lane = t & 63;
    const int wid  = t >> 6;
    if (lane == 0) { s[0][wid] = r; s[1][wid] = cf; s[2][wid] = no; s[3][wid] = cl; }
    __syncthreads();
    if (t == 0) {
        double R = 0, CF = 0, NO = 0, CL = 0;
        #pragma unroll
        for (int w = 0; w < 4; ++w) { R += s[0][w]; CF += s[1][w]; NO += s[2][w]; CL += s[3][w]; }
        const float invN = 1.0f / (float)N_BATCH;
        const float reg   = (float)R  * invN;
        const float conf  = (float)CF * invN;
        const float noobj = (float)NO * invN;
        const float cls   = (float)CL * invN;
        out[0] = 5.0f * reg + conf + 0.5f * noobj + cls;
        out[1] = reg;
        out[2] = conf;
        out[3] = noobj;
        out[4] = cls;
    }
}

extern "C" void kernel_launch(void* const* d_in, const int* in_sizes, int n_in,
                              void* d_out, int out_size, void* d_ws, size_t ws_size,
                              hipStream_t stream) {
    const float* pred = (const float*)d_in[0];
    const float* tbox = (const float*)d_in[1];
    const float* tcls = (const float*)d_in[2];
    const void*  mask = (const void*)d_in[3];
    float* out = (float*)d_out;

    float4* partial = (float4*)d_ws;                      // 3136 * 16 B
    int* flag = (int*)((char*)d_ws + NBLOCKS * sizeof(float4));

    detect_flag<<<1, 256, 0, stream>>>((const unsigned int*)mask, flag);
    yolo_loss_main<<<NBLOCKS, 256, 0, stream>>>(pred, tbox, tcls, mask, flag, partial);
    yolo_finalize<<<1, 256, 0, stream>>>(partial, out);
}